// Round 1
// baseline (14084.070 us; speedup 1.0000x reference)
//
#include <hip/hip_runtime.h>
#include <stdint.h>

// FPS: B=32, C=3, N=131072, M=2048, f32.
// 32 batches x 8 WGs x 1024 threads; 16 points/thread held in registers.

#define B_   32
#define N_   131072
#define M_   2048
#define WPB  8          // workgroups per batch
#define T_   1024       // threads per workgroup
#define PTS  16         // points per thread (N_/WPB/T_)
#define ITERS (M_ - 1)

#define CNT_STRIDE 32   // u32 stride per batch counter (cacheline separation)

__device__ __forceinline__ void red_pair(float& v, unsigned& i, int off) {
    float    ov = __shfl_down(v, off);
    unsigned oi = __shfl_down(i, off);
    bool take = (ov > v) || (ov == v && oi < i);
    v = take ? ov : v;
    i = take ? oi : i;
}

__global__ void fps_init(unsigned* ws_u32, int nwords) {
    int i = blockIdx.x * blockDim.x + threadIdx.x;
    for (; i < nwords; i += gridDim.x * blockDim.x) ws_u32[i] = 0u;
}

__global__ void __launch_bounds__(T_, 4)
fps_main(const float* __restrict__ x, float* __restrict__ y,
         unsigned* __restrict__ cnt, float* __restrict__ cand) {
    const int bid = blockIdx.x;
    const int b   = bid & (B_ - 1);   // batch; WGs of a batch are bid%32 equal -> same XCD under round-robin
    const int wl  = bid >> 5;         // 0..7 local wg id within batch
    const int tid = threadIdx.x;
    const int lane = tid & 63;
    const int wave = tid >> 6;

    const float* __restrict__ xb = x + (size_t)b * 3u * N_;
    float* __restrict__ yb = y + (size_t)b * 3u * M_;
    const unsigned pbase = (unsigned)(wl * (N_ / WPB) + tid);

    // register-resident point coords + running min-dists
    float X[PTS], Y[PTS], Z[PTS], D[PTS];
#pragma unroll
    for (int k = 0; k < PTS; ++k) {
        unsigned p = pbase + (unsigned)(k * T_);
        X[k] = xb[p];
        Y[k] = xb[N_ + p];
        Z[k] = xb[2 * N_ + p];
        D[k] = INFINITY;
    }

    // first selected point is index 0
    float lx = xb[0], ly = xb[N_], lz = xb[2 * N_];
    if (wl == 0 && tid == 0) { yb[0] = lx; yb[M_] = ly; yb[2 * M_] = lz; }

    __shared__ float    s_wv[16];
    __shared__ unsigned s_wi[16];
    __shared__ float    s_bc[8];  // [0]=wg best v, [1]=wg best idx(bits), [2..4]=wg best coords, [5..7]=batch winner coords

    unsigned* mycnt = cnt + b * CNT_STRIDE;

    for (int it = 0; it < ITERS; ++it) {
        // ---- update min-dists + thread-local argmax (first-index ties) ----
        float bv = -INFINITY; unsigned bi = 0u;
#pragma unroll
        for (int k = 0; k < PTS; ++k) {
            float dx = X[k] - lx;
            float dy = Y[k] - ly;
            float dz = Z[k] - lz;
            // match XLA: ((dx*dx)+(dy*dy))+(dz*dz), each individually rounded, no FMA
            float d  = __fadd_rn(__fadd_rn(__fmul_rn(dx, dx), __fmul_rn(dy, dy)),
                                 __fmul_rn(dz, dz));
            float nd = fminf(D[k], d);
            D[k] = nd;
            bool t = nd > bv;           // strict > keeps earliest index within thread (ascending k)
            bv = t ? nd : bv;
            bi = t ? (pbase + (unsigned)(k * T_)) : bi;
        }

        // ---- wave reduce (64 lanes) ----
        red_pair(bv, bi, 32); red_pair(bv, bi, 16); red_pair(bv, bi, 8);
        red_pair(bv, bi, 4);  red_pair(bv, bi, 2);  red_pair(bv, bi, 1);
        if (lane == 0) { s_wv[wave] = bv; s_wi[wave] = bi; }
        __syncthreads();

        // ---- block reduce (16 waves) in wave 0 ----
        if (wave == 0) {
            float    v  = (lane < 16) ? s_wv[lane] : -INFINITY;
            unsigned i2 = (lane < 16) ? s_wi[lane] : 0xFFFFFFFFu;
            red_pair(v, i2, 8); red_pair(v, i2, 4); red_pair(v, i2, 2); red_pair(v, i2, 1);
            if (lane == 0) { s_bc[0] = v; s_bc[1] = __uint_as_float(i2); }
        }
        __syncthreads();

        // ---- owner thread deposits the wg-best point's coords ----
        unsigned wgbi = __float_as_uint(s_bc[1]);
#pragma unroll
        for (int k = 0; k < PTS; ++k) {
            if (pbase + (unsigned)(k * T_) == wgbi) {
                s_bc[2] = X[k]; s_bc[3] = Y[k]; s_bc[4] = Z[k];
            }
        }
        __syncthreads();

        // ---- publish candidate record, arrive at batch barrier, spin ----
        const int par = it & 1;
        float* rec = cand + (size_t)(((b * 2 + par) * WPB + wl) * 8);
        if (tid == 0) {
            __hip_atomic_store(&rec[0], s_bc[0], __ATOMIC_RELAXED, __HIP_MEMORY_SCOPE_AGENT);
            __hip_atomic_store(&rec[1], s_bc[1], __ATOMIC_RELAXED, __HIP_MEMORY_SCOPE_AGENT);
            __hip_atomic_store(&rec[2], s_bc[2], __ATOMIC_RELAXED, __HIP_MEMORY_SCOPE_AGENT);
            __hip_atomic_store(&rec[3], s_bc[3], __ATOMIC_RELAXED, __HIP_MEMORY_SCOPE_AGENT);
            __hip_atomic_store(&rec[4], s_bc[4], __ATOMIC_RELAXED, __HIP_MEMORY_SCOPE_AGENT);
            __hip_atomic_fetch_add(mycnt, 1u, __ATOMIC_RELEASE, __HIP_MEMORY_SCOPE_AGENT);
            const unsigned target = (unsigned)(WPB * (it + 1));
            while (__hip_atomic_load(mycnt, __ATOMIC_ACQUIRE, __HIP_MEMORY_SCOPE_AGENT) < target) {
                __builtin_amdgcn_s_sleep(1);
            }
        }
        __syncthreads();

        // ---- read the 8 candidates, pick batch winner (value, tie -> lower idx) ----
        if (wave == 0) {
            float v = -INFINITY; unsigned i2 = 0xFFFFFFFFu;
            float cx = 0.f, cy = 0.f, cz = 0.f;
            if (lane < WPB) {
                const float* r2 = cand + (size_t)(((b * 2 + par) * WPB + lane) * 8);
                v  = __hip_atomic_load(&r2[0], __ATOMIC_RELAXED, __HIP_MEMORY_SCOPE_AGENT);
                i2 = __float_as_uint(__hip_atomic_load(&r2[1], __ATOMIC_RELAXED, __HIP_MEMORY_SCOPE_AGENT));
                cx = __hip_atomic_load(&r2[2], __ATOMIC_RELAXED, __HIP_MEMORY_SCOPE_AGENT);
                cy = __hip_atomic_load(&r2[3], __ATOMIC_RELAXED, __HIP_MEMORY_SCOPE_AGENT);
                cz = __hip_atomic_load(&r2[4], __ATOMIC_RELAXED, __HIP_MEMORY_SCOPE_AGENT);
            }
            for (int off = 4; off >= 1; off >>= 1) {
                float    ov = __shfl_down(v, off);
                unsigned oi = __shfl_down(i2, off);
                float ox = __shfl_down(cx, off);
                float oy = __shfl_down(cy, off);
                float oz = __shfl_down(cz, off);
                bool take = (ov > v) || (ov == v && oi < i2);
                v = take ? ov : v; i2 = take ? oi : i2;
                cx = take ? ox : cx; cy = take ? oy : cy; cz = take ? oz : cz;
            }
            if (lane == 0) { s_bc[5] = cx; s_bc[6] = cy; s_bc[7] = cz; }
        }
        __syncthreads();

        lx = s_bc[5]; ly = s_bc[6]; lz = s_bc[7];
        if (wl == 0 && tid == 0) {
            yb[it + 1]          = lx;
            yb[M_ + it + 1]     = ly;
            yb[2 * M_ + it + 1] = lz;
        }
    }
}

extern "C" void kernel_launch(void* const* d_in, const int* in_sizes, int n_in,
                              void* d_out, int out_size, void* d_ws, size_t ws_size,
                              hipStream_t stream) {
    const float* x = (const float*)d_in[0];
    float* y = (float*)d_out;

    unsigned* cnt  = (unsigned*)d_ws;                                // 32 * CNT_STRIDE u32 = 4 KiB
    float*    cand = (float*)((char*)d_ws + B_ * CNT_STRIDE * 4);    // 32*2*8*8 f32 = 16 KiB

    // zero the barrier counters (ws is poisoned to 0xAA before every launch)
    fps_init<<<4, 256, 0, stream>>>((unsigned*)d_ws, B_ * CNT_STRIDE);

    fps_main<<<B_ * WPB, T_, 0, stream>>>(x, y, cnt, cand);
}